// Round 15
// baseline (972.714 us; speedup 1.0000x reference)
//
#include <hip/hip_runtime.h>

// QINCoStep fused kernel — round 15: R14 design (16x16x32 MFMA, 16 codes/wave,
// 4 blocks/n, pure per-lane B-frag repacks) with fixes:
//   (1) b1_s[256..511] staging restored (R14's bug: block b=1 read uninit LDS)
//   (2) exact 64-bit argmin keys + device atomicMin (no 24-bit truncation)
//   (3) launch_bounds(256,3): live set ~150 regs < 512/3 cap -> 3 waves/SIMD
// Winner row recomputed in f32 by fin kernel. f16x3 numerics as R5-R13.
// D=128, K=256, HID=256, NBLK=2, N=4096.
// Outputs (flat f32): codes[N] | x_hat_new[N*D] | r[N*D] | c_sel[N*D]

#define QD    128
#define QK    256
#define QHID  256
#define QNBLK 2
#define QN    4096

typedef _Float16 f16;
typedef _Float16 f16x8 __attribute__((ext_vector_type(8)));
typedef float    f32x4 __attribute__((ext_vector_type(4)));
typedef unsigned long long u64;

// ---- workspace layout (bytes) ----
#define WS_CPART 0          // f32 [256][128]                      131072
#define WS_W1    131072     // f16 frags [2b][8hc][16 fi][64][8]   262144
#define WS_W2    393216     // f16 frags [2b][8hc][16 fi][64][8]   262144
#define WS_KEY   655360     // u64 [4096]                           32768
                            // end 688128 (< proven 720896)

static __device__ __forceinline__ f32x4 MF16(f16x8 a, f16x8 b, f32x4 c) {
    return __builtin_amdgcn_mfma_f32_16x16x32_f16(a, b, c, 0, 0, 0);
}
static __device__ __forceinline__ unsigned pkrtz(float a, float b) {
    return __builtin_bit_cast(unsigned, __builtin_amdgcn_cvt_pkrtz(a, b));
}
static __device__ __forceinline__ float f32lo(unsigned p) {
    return (float)__builtin_bit_cast(f16, (unsigned short)(p & 0xffffu));
}
static __device__ __forceinline__ float f32hi(unsigned p) {
    return (float)__builtin_bit_cast(f16, (unsigned short)(p >> 16));
}
static __device__ __forceinline__ void gload_lds16(const void* g, void* l) {
    __builtin_amdgcn_global_load_lds(
        (const __attribute__((address_space(1))) unsigned*)g,
        (__attribute__((address_space(3))) unsigned*)l, 16, 0, 0);
}

// Build hi/lo B-frag pair from two acc tiles (a0 = tile 2c, a1 = tile 2c+1).
// kslot(lg,j) = 16*(j>>2) + 4*lg + (j&3): each lane uses ONLY its own regs.
static __device__ __forceinline__ void mk_frag(f32x4 a0, f32x4 a1,
                                               f16x8& fh, f16x8& fl) {
    unsigned h0 = pkrtz(a0[0], a0[1]);
    unsigned h1 = pkrtz(a0[2], a0[3]);
    unsigned h2 = pkrtz(a1[0], a1[1]);
    unsigned h3 = pkrtz(a1[2], a1[3]);
    unsigned l0 = pkrtz(a0[0] - f32lo(h0), a0[1] - f32hi(h0));
    unsigned l1 = pkrtz(a0[2] - f32lo(h1), a0[3] - f32hi(h1));
    unsigned l2 = pkrtz(a1[0] - f32lo(h2), a1[1] - f32hi(h2));
    unsigned l3 = pkrtz(a1[2] - f32lo(h3), a1[3] - f32hi(h3));
    fh = __builtin_bit_cast(f16x8, make_uint4(h0, h1, h2, h3));
    fl = __builtin_bit_cast(f16x8, make_uint4(l0, l1, l2, l3));
}

// ---------------------------------------------------------------------------
// Prep: key init + cpart (f32) + W1/W2 as 16x16x32 A-frag hi/lo planes,
// kslot map kslot(lg,j) = 16*(j>>2) + 4*lg + (j&3) (A/B share it).
// ---------------------------------------------------------------------------
__global__ __launch_bounds__(128) void qinco_prep(
    const float* __restrict__ cb, const float* __restrict__ Wp,
    const float* __restrict__ bp, const float* __restrict__ W1,
    const float* __restrict__ W2, char* __restrict__ ws) {
    const int blk = blockIdx.x;
    const int t = threadIdx.x;
    __shared__ float row[QD];

    if (blk < 32)
        ((u64*)(ws + WS_KEY))[blk * 128 + t] = ~0ull;   // re-init every call

    if (blk < 256) {
        float* cpart = (float*)(ws + WS_CPART);
        row[t] = cb[blk * QD + t];
        __syncthreads();
        float acc = bp[t];
        const float* wr = Wp + (size_t)t * (2 * QD) + QD;
        #pragma unroll 8
        for (int e = 0; e < QD; ++e) acc = fmaf(row[e], wr[e], acc);
        cpart[blk * QD + t] = acc;
    } else if (blk < 384) {
        if (t < 64) {
            const int u = blk - 256;          // b*64 + hc*8 + dc*2 + ht
            const int b = u >> 6, hc = (u >> 3) & 7, dc = (u >> 1) & 3, ht = u & 1;
            const int lg = t >> 4;
            const int h = hc * 32 + ht * 16 + (t & 15);
            f16* dsth = (f16*)(ws + WS_W1
                        + (size_t)(((b * 8 + hc) * 16 + dc * 4 + ht * 2) * 1024)
                        + (size_t)t * 16);
            f16* dstl = dsth + 512;           // +1024 B = next frag (lo plane)
            #pragma unroll
            for (int j = 0; j < 8; ++j) {
                const int d = dc * 32 + 16 * (j >> 2) + 4 * lg + (j & 3);
                float wv = W1[((size_t)b * QHID + h) * QD + d];
                f16 hi = (f16)wv;
                dsth[j] = hi;
                dstl[j] = (f16)(wv - (float)hi);
            }
        }
    } else {
        if (t < 64) {
            const int u = blk - 384;          // b*64 + hc*8 + dt
            const int b = u >> 6, hc = (u >> 3) & 7, dt = u & 7;
            const int lg = t >> 4;
            const int d = dt * 16 + (t & 15);
            f16* dsth = (f16*)(ws + WS_W2
                        + (size_t)(((b * 8 + hc) * 16 + dt * 2) * 1024)
                        + (size_t)t * 16);
            f16* dstl = dsth + 512;
            #pragma unroll
            for (int j = 0; j < 8; ++j) {
                const int h = hc * 32 + 16 * (j >> 2) + 4 * lg + (j & 3);
                float wv = W2[((size_t)b * QD + d) * QHID + h];
                f16 hi = (f16)wv;
                dsth[j] = hi;
                dstl[j] = (f16)(wv - (float)hi);
            }
        }
    }
}

// ---------------------------------------------------------------------------
// Main: grid 16384 (4 blocks per n, 64 codes each); 4 waves x 16 codes.
// Acc: C^T[d][code] in 8 16x16 tiles: lane holds d = dt*16+4*lg+q, col l&15.
// W1 LDS double-buffered (16KB tiles, 1 barrier/iter); W2 global->reg.
// ---------------------------------------------------------------------------
__global__ __launch_bounds__(256, 3) void qinco_main(
    const float* __restrict__ x, const float* __restrict__ xh,
    const float* __restrict__ Wp,
    const float* __restrict__ b1g, const float* __restrict__ b2g,
    char* __restrict__ ws, float* __restrict__ out) {

    __shared__ f16 wbuf[2][16][64][8];   // 32 KiB: 2 bufs x 16 frags x 1KB
    __shared__ float b1_s[512];
    __shared__ float b2_s[256];
    __shared__ u64 red_k[64];
    __shared__ float xp_s[QD], xh_s[QD], r_s[QD];

    const int n = blockIdx.x >> 2;
    const int h4 = blockIdx.x & 3;
    const int t = threadIdx.x;
    const int w = t >> 6;
    const int l = t & 63;
    const int lg = l >> 4;
    const int codebase = h4 * 64 + w * 16;

    const float* cpart = (const float*)(ws + WS_CPART);

    // ---- stage smalls (FIX: full 512-entry b1) + issue W1[iter0] staging ----
    b1_s[t] = b1g[t];
    b1_s[t + 256] = b1g[t + 256];
    b2_s[t] = b2g[t];
    if (t < QD) {
        float xv  = x[(size_t)n * QD + t];
        float xhv = xh[(size_t)n * QD + t];
        xh_s[t] = xhv;
        r_s[t]  = xv - xhv;
    }
    {
        const char* s0 = ws + WS_W1 + (size_t)(w * 4) * 1024 + (size_t)l * 16;
        char* d0 = (char*)(&wbuf[0][w * 4][0][0]);
        #pragma unroll
        for (int ii = 0; ii < 4; ++ii)
            gload_lds16(s0 + (size_t)ii * 1024, d0 + (size_t)ii * 1024);
    }
    __syncthreads();

    // ---- x_part[d] = sum_e xh[e] * Wp[d,e] ----
    if (t < QD) {
        const float4* wr = (const float4*)(Wp + (size_t)t * (2 * QD));
        const float4* xv = (const float4*)xh_s;
        float acc = 0.f;
        #pragma unroll
        for (int j = 0; j < QD / 4; ++j) {
            float4 a = wr[j], bv = xv[j];
            acc = fmaf(a.x, bv.x, acc);
            acc = fmaf(a.y, bv.y, acc);
            acc = fmaf(a.z, bv.z, acc);
            acc = fmaf(a.w, bv.w, acc);
        }
        xp_s[t] = acc;
    }
    __syncthreads();

    // ---- init C^T acc: 8 tiles of 16x16 ----
    f32x4 Cacc[8];
    {
        const int code = codebase + (l & 15);
        const float* cprow = cpart + (size_t)code * QD;
        #pragma unroll
        for (int dt = 0; dt < 8; ++dt) {
            const int d0 = dt * 16 + 4 * lg;
            float4 cp  = *(const float4*)(cprow + d0);
            float4 xp4 = *(const float4*)(xp_s + d0);
            Cacc[dt] = (f32x4){cp.x + xp4.x, cp.y + xp4.y,
                               cp.z + xp4.z, cp.w + xp4.w};
        }
    }

    f16x8 cfh[4], cfl[4];

    // ---- main loop: 16 iters = 2 blocks x 8 h-chunks ----
    #pragma unroll 1
    for (int iter = 0; iter < 16; ++iter) {
        const int b = iter >> 3;
        const int hc = iter & 7;
        const int buf = iter & 1;

        asm volatile("s_waitcnt vmcnt(0) lgkmcnt(0)" ::: "memory");
        __builtin_amdgcn_s_barrier();
        asm volatile("" ::: "memory");

        // W2 chunk0 prefetch (global, L1/L2-resident; covered by GEMM1)
        const char* pw2 = ws + WS_W2 + (size_t)((b * 8 + hc) * 16) * 1024
                        + (size_t)l * 16;
        f16x8 A0h[4], A0l[4];
        #pragma unroll
        for (int dt = 0; dt < 4; ++dt) {
            A0h[dt] = *(const f16x8*)(pw2 + (size_t)(2 * dt) * 1024);
            A0l[dt] = *(const f16x8*)(pw2 + (size_t)(2 * dt + 1) * 1024);
        }

        // stage W1[iter+1] into other buf (its readers finished at barrier)
        if (iter < 15) {
            const int t2 = iter + 1;
            const char* s0 = ws + WS_W1
                           + (size_t)((((t2 >> 3) * 8 + (t2 & 7)) * 16 + w * 4)) * 1024
                           + (size_t)l * 16;
            char* d0 = (char*)(&wbuf[buf ^ 1][w * 4][0][0]);
            #pragma unroll
            for (int ii = 0; ii < 4; ++ii)
                gload_lds16(s0 + (size_t)ii * 1024, d0 + (size_t)ii * 1024);
        }

        // rebuild C fragments at the start of each residual block
        if (hc == 0) {
            #pragma unroll
            for (int c = 0; c < 4; ++c)
                mk_frag(Cacc[2 * c], Cacc[2 * c + 1], cfh[c], cfl[c]);
        }

        // ---- GEMM1: H^T (2 tiles of 16h x 16code), f16x3 ----
        f32x4 Ha0, Ha1;
        {
            float4 bv0 = *(const float4*)(b1_s + b * 256 + hc * 32 + 4 * lg);
            float4 bv1 = *(const float4*)(b1_s + b * 256 + hc * 32 + 16 + 4 * lg);
            Ha0 = (f32x4){bv0.x, bv0.y, bv0.z, bv0.w};
            Ha1 = (f32x4){bv1.x, bv1.y, bv1.z, bv1.w};
        }
        const char* wb1 = (const char*)(&wbuf[buf][0][0][0]) + (size_t)l * 16;
        __builtin_amdgcn_s_setprio(1);
        #pragma unroll
        for (int dc = 0; dc < 4; ++dc) {
            f16x8 w1h0 = *(const f16x8*)(wb1 + (size_t)(dc * 4 + 0) * 1024);
            f16x8 w1l0 = *(const f16x8*)(wb1 + (size_t)(dc * 4 + 1) * 1024);
            f16x8 w1h1 = *(const f16x8*)(wb1 + (size_t)(dc * 4 + 2) * 1024);
            f16x8 w1l1 = *(const f16x8*)(wb1 + (size_t)(dc * 4 + 3) * 1024);
            Ha0 = MF16(w1h0, cfh[dc], Ha0);
            Ha1 = MF16(w1h1, cfh[dc], Ha1);
            Ha0 = MF16(w1l0, cfh[dc], Ha0);
            Ha1 = MF16(w1l1, cfh[dc], Ha1);
            Ha0 = MF16(w1h0, cfl[dc], Ha0);
            Ha1 = MF16(w1h1, cfl[dc], Ha1);
        }
        __builtin_amdgcn_s_setprio(0);

        // relu + hf build (pure per-lane repack)
        #pragma unroll
        for (int q = 0; q < 4; ++q) {
            Ha0[q] = fmaxf(Ha0[q], 0.f);
            Ha1[q] = fmaxf(Ha1[q], 0.f);
        }
        f16x8 hfh, hfl;
        mk_frag(Ha0, Ha1, hfh, hfl);

        // ---- GEMM2 chunk0 (dt 0..3) ----
        __builtin_amdgcn_s_setprio(1);
        #pragma unroll
        for (int dt = 0; dt < 4; ++dt) {
            Cacc[dt] = MF16(A0h[dt], hfh, Cacc[dt]);
            Cacc[dt] = MF16(A0l[dt], hfh, Cacc[dt]);
            Cacc[dt] = MF16(A0h[dt], hfl, Cacc[dt]);
        }
        __builtin_amdgcn_s_setprio(0);

        // W2 chunk1 prefetch + GEMM2 chunk1 (dt 4..7)
        f16x8 A1h[4], A1l[4];
        #pragma unroll
        for (int dt = 0; dt < 4; ++dt) {
            A1h[dt] = *(const f16x8*)(pw2 + (size_t)(2 * (dt + 4)) * 1024);
            A1l[dt] = *(const f16x8*)(pw2 + (size_t)(2 * (dt + 4) + 1) * 1024);
        }
        __builtin_amdgcn_s_setprio(1);
        #pragma unroll
        for (int dt = 0; dt < 4; ++dt) {
            Cacc[dt + 4] = MF16(A1h[dt], hfh, Cacc[dt + 4]);
            Cacc[dt + 4] = MF16(A1l[dt], hfh, Cacc[dt + 4]);
            Cacc[dt + 4] = MF16(A1h[dt], hfl, Cacc[dt + 4]);
        }
        __builtin_amdgcn_s_setprio(0);

        // end of residual block: + b2
        if (hc == 7) {
            #pragma unroll
            for (int dt = 0; dt < 8; ++dt) {
                float4 bv = *(const float4*)(b2_s + b * QD + dt * 16 + 4 * lg);
                Cacc[dt][0] += bv.x;
                Cacc[dt][1] += bv.y;
                Cacc[dt][2] += bv.z;
                Cacc[dt][3] += bv.w;
            }
        }
    } // iter

    // ---- distances: lane holds 32 of 128 d for its code ----
    float pa = 0.f, pb = 0.f, pc = 0.f, pdm = 0.f;
    #pragma unroll
    for (int dt = 0; dt < 8; ++dt) {
        float4 rr = *(const float4*)(r_s + dt * 16 + 4 * lg);
        float t0 = rr.x - Cacc[dt][0];
        float t1 = rr.y - Cacc[dt][1];
        float t2 = rr.z - Cacc[dt][2];
        float t3 = rr.w - Cacc[dt][3];
        pa = fmaf(t0, t0, pa);
        pb = fmaf(t1, t1, pb);
        pc = fmaf(t2, t2, pc);
        pdm = fmaf(t3, t3, pdm);
    }
    float pd = (pa + pb) + (pc + pdm);
    pd += __shfl_xor(pd, 16);
    pd += __shfl_xor(pd, 32);
    if (l < 16) {
        const int lc = w * 16 + l;     // local code 0..63
        red_k[lc] = ((u64)__float_as_uint(pd) << 32)
                  | (u64)(unsigned)(h4 * 64 + lc);   // exact dist | code
    }
    __syncthreads();

    // u64 min tree over 64 keys (min dist; tie -> smaller code = first index)
    for (int off = 32; off > 0; off >>= 1) {
        if (t < off) {
            u64 a = red_k[t], b2v = red_k[t + off];
            red_k[t] = (b2v < a) ? b2v : a;
        }
        __syncthreads();
    }
    if (t == 0)
        atomicMin((u64*)(ws + WS_KEY) + n, red_k[0]);
}

// ---------------------------------------------------------------------------
// Fin: read winner key per n; recompute winner's C row in pure f32 from
// original weights (4 n per block for weight reuse); write all outputs.
// ---------------------------------------------------------------------------
__global__ __launch_bounds__(256) void qinco_fin(
    const float* __restrict__ x, const float* __restrict__ xh,
    const float* __restrict__ Wp,
    const float* __restrict__ W1, const float* __restrict__ b1,
    const float* __restrict__ W2, const float* __restrict__ b2,
    const char* __restrict__ ws, float* __restrict__ out) {

    __shared__ float xh4[4][QD];
    __shared__ float C[4][QD];
    __shared__ float s_l[QHID][4];
    __shared__ int code_s[4];

    const int t = threadIdx.x;
    const int ng = blockIdx.x * 4;
    const u64* keys = (const u64*)(ws + WS_KEY);
    const float* cpart = (const float*)(ws + WS_CPART);

    if (t < 4) code_s[t] = (int)(keys[ng + t] & 255u);
    for (int i = t; i < 4 * QD; i += 256)
        xh4[i >> 7][i & 127] = xh[(size_t)(ng + (i >> 7)) * QD + (i & 127)];
    __syncthreads();

    const int d = t & 127, ph = t >> 7;

    // C = x_part + cpart[code]
    #pragma unroll
    for (int k2 = 0; k2 < 2; ++k2) {
        const int nl = ph + 2 * k2;
        float acc = 0.f;
        const float4* wr = (const float4*)(Wp + (size_t)d * (2 * QD));
        #pragma unroll 8
        for (int e4 = 0; e4 < 32; ++e4) {
            float4 wv = wr[e4];
            acc = fmaf(wv.x, xh4[nl][e4 * 4 + 0], acc);
            acc = fmaf(wv.y, xh4[nl][e4 * 4 + 1], acc);
            acc = fmaf(wv.z, xh4[nl][e4 * 4 + 2], acc);
            acc = fmaf(wv.w, xh4[nl][e4 * 4 + 3], acc);
        }
        C[nl][d] = acc + cpart[(size_t)code_s[nl] * QD + d];
    }
    __syncthreads();

    #pragma unroll 1
    for (int b = 0; b < QNBLK; ++b) {
        // layer1: thread = h
        {
            const int h = t;
            float acc[4];
            float bb = b1[b * QHID + h];
            acc[0] = acc[1] = acc[2] = acc[3] = bb;
            const float4* wr = (const float4*)(W1 + ((size_t)b * QHID + h) * QD);
            #pragma unroll 4
            for (int e4 = 0; e4 < 32; ++e4) {
                float4 wv = wr[e4];
                #pragma unroll
                for (int nl = 0; nl < 4; ++nl) {
                    acc[nl] = fmaf(wv.x, C[nl][e4 * 4 + 0], acc[nl]);
                    acc[nl] = fmaf(wv.y, C[nl][e4 * 4 + 1], acc[nl]);
                    acc[nl] = fmaf(wv.z, C[nl][e4 * 4 + 2], acc[nl]);
                    acc[nl] = fmaf(wv.w, C[nl][e4 * 4 + 3], acc[nl]);
                }
            }
            #pragma unroll
            for (int nl = 0; nl < 4; ++nl)
                s_l[h][nl] = fmaxf(acc[nl], 0.f);
        }
        __syncthreads();
        // layer2: thread = (d, two nl)
        {
            float a0 = 0.f, a1 = 0.f;
            const int nl0 = ph, nl1 = ph + 2;
            const float4* wr = (const float4*)(W2 + ((size_t)b * QD + d) * QHID);
            #pragma unroll 4
            for (int h4i = 0; h4i < 64; ++h4i) {
                float4 wv = wr[h4i];
                a0 = fmaf(wv.x, s_l[h4i * 4 + 0][nl0], a0);
                a1 = fmaf(wv.x, s_l[h4i * 4 + 0][nl1], a1);
                a0 = fmaf(wv.y, s_l[h4i * 4 + 1][nl0], a0);
                a1 = fmaf(wv.y, s_l[h4i * 4 + 1][nl1], a1);
                a0 = fmaf(wv.z, s_l[h4i * 4 + 2][nl0], a0);
                a1 = fmaf(wv.z, s_l[h4i * 4 + 2][nl1], a1);
                a0 = fmaf(wv.w, s_l[h4i * 4 + 3][nl0], a0);
                a1 = fmaf(wv.w, s_l[h4i * 4 + 3][nl1], a1);
            }
            float bv = b2[b * QD + d];
            C[nl0][d] += a0 + bv;
            C[nl1][d] += a1 + bv;
        }
        __syncthreads();
    }

    // ---- outputs ----
    #pragma unroll
    for (int k2 = 0; k2 < 2; ++k2) {
        const int nl = ph + 2 * k2;
        const size_t nn = (size_t)(ng + nl);
        float cs = C[nl][d];
        float xhv = xh4[nl][d];
        float xv = x[nn * QD + d];
        out[QN + nn * QD + d]                        = xhv + cs;  // x_hat_new
        out[QN + (size_t)QN * QD + nn * QD + d]      = xv - xhv;  // r
        out[QN + 2 * (size_t)QN * QD + nn * QD + d]  = cs;        // c_sel
    }
    if (t < 4) out[ng + t] = (float)code_s[t];
}

// ---------------------------------------------------------------------------
extern "C" void kernel_launch(void* const* d_in, const int* in_sizes, int n_in,
                              void* d_out, int out_size, void* d_ws, size_t ws_size,
                              hipStream_t stream) {
    const float* x   = (const float*)d_in[0];
    const float* xh  = (const float*)d_in[1];
    const float* cb  = (const float*)d_in[2];
    const float* Wp  = (const float*)d_in[3];
    const float* bp  = (const float*)d_in[4];
    const float* W1  = (const float*)d_in[5];
    const float* b1  = (const float*)d_in[6];
    const float* W2  = (const float*)d_in[7];
    const float* b2  = (const float*)d_in[8];
    float* out = (float*)d_out;

    qinco_prep<<<512, 128, 0, stream>>>(cb, Wp, bp, W1, W2, (char*)d_ws);
    qinco_main<<<4 * QN, 256, 0, stream>>>(x, xh, Wp, b1, b2, (char*)d_ws, out);
    qinco_fin<<<QN / 4, 256, 0, stream>>>(x, xh, Wp, W1, b1, W2, b2,
                                          (const char*)d_ws, out);
}

// Round 16
// 749.713 us; speedup vs baseline: 1.2974x; 1.2974x over previous
//
#include <hip/hip_runtime.h>

// QINCoStep fused kernel — round 16: R8 base + cross-iteration interleave:
// GEMM1(i) interleaved with GEMM2(i-1) (two independent MFMA chains between
// LDS reads -> ds_read latency covered). W2 staged one iter behind W1
// (2+2 16KB buffers, same 69.5KB LDS, 1 barrier/iter). Numerics f16x3,
// 32x32x16, identical to R5-R13. Finisher scheme = R8.
// D=128, K=256, HID=256, NBLK=2, N=4096.
// Outputs (flat f32): codes[N] | x_hat_new[N*D] | r[N*D] | c_sel[N*D]

#define QD    128
#define QK    256
#define QHID  256
#define QNBLK 2
#define QN    4096

typedef _Float16 f16;
typedef _Float16 f16x8  __attribute__((ext_vector_type(8)));
typedef float    f32x16 __attribute__((ext_vector_type(16)));
typedef unsigned u32x2  __attribute__((ext_vector_type(2)));

// ---- workspace layout (bytes) ----
#define WS_CPART 0
#define WS_W1H   131072     // f16 [128 cids][64][8]; W1L at +131072
#define WS_W2H   393216     // W2L at +131072
#define WS_PART  655360     // float2[4096][2] = 64 KiB; end 720896

// ---- dynamic LDS layout (bytes) ----
#define L_W1B   0           // 2 x 16KB W1 tiles [hi 8K | lo 8K]
#define L_W2B   32768       // 2 x 16KB W2 tiles [hi 8K | lo 8K]
#define L_B1    65536       // f32[512]
#define L_B2    67584       // f32[256]
#define L_REDD  68608       // f32[128]
#define L_REDI  69120       // i32[128]
#define L_XP    69632       // f32[128]
#define L_XH    70144       // f32[128]
#define L_RS    70656       // f32[128]
#define L_TOTAL 71168

static __device__ __forceinline__ f32x16 MF32(f16x8 a, f16x8 b, f32x16 c) {
    return __builtin_amdgcn_mfma_f32_32x32x16_f16(a, b, c, 0, 0, 0);
}
static __device__ __forceinline__ unsigned pkrtz(float a, float b) {
    return __builtin_bit_cast(unsigned, __builtin_amdgcn_cvt_pkrtz(a, b));
}
static __device__ __forceinline__ float f32lo(unsigned p) {
    return (float)__builtin_bit_cast(f16, (unsigned short)(p & 0xffffu));
}
static __device__ __forceinline__ float f32hi(unsigned p) {
    return (float)__builtin_bit_cast(f16, (unsigned short)(p >> 16));
}
static __device__ __forceinline__ u32x2 plswap(unsigned a, unsigned b) {
    return __builtin_amdgcn_permlane32_swap(a, b, false, false);
}
static __device__ __forceinline__ void gload_lds16(const void* g, void* l) {
    __builtin_amdgcn_global_load_lds(
        (const __attribute__((address_space(1))) unsigned*)g,
        (__attribute__((address_space(3))) unsigned*)l, 16, 0, 0);
}

// Build hi/lo B-fragments (k-chunk of 16) from accumulator regs RB..RB+7.
template<int RB>
static __device__ __forceinline__ void split_frags(f32x16 a, f16x8& fh, f16x8& fl) {
    unsigned P0 = pkrtz(a[RB + 0], a[RB + 1]);
    unsigned P1 = pkrtz(a[RB + 2], a[RB + 3]);
    unsigned Q0 = pkrtz(a[RB + 4], a[RB + 5]);
    unsigned Q1 = pkrtz(a[RB + 6], a[RB + 7]);
    unsigned L0 = pkrtz(a[RB + 0] - f32lo(P0), a[RB + 1] - f32hi(P0));
    unsigned L1 = pkrtz(a[RB + 2] - f32lo(P1), a[RB + 3] - f32hi(P1));
    unsigned L2 = pkrtz(a[RB + 4] - f32lo(Q0), a[RB + 5] - f32hi(Q0));
    unsigned L3 = pkrtz(a[RB + 6] - f32lo(Q1), a[RB + 7] - f32hi(Q1));
    u32x2 s0 = plswap(P0, Q0);
    u32x2 s1 = plswap(P1, Q1);
    u32x2 t0 = plswap(L0, L2);
    u32x2 t1 = plswap(L1, L3);
    uint4 hw = make_uint4(s0.x, s1.x, s0.y, s1.y);
    uint4 lw = make_uint4(t0.x, t1.x, t0.y, t1.y);
    fh = __builtin_bit_cast(f16x8, hw);
    fl = __builtin_bit_cast(f16x8, lw);
}

// ---------------------------------------------------------------------------
// Prep: cpart (f32) + weights as A-fragment hi/lo f16 planes (R8 verbatim).
// ---------------------------------------------------------------------------
__global__ __launch_bounds__(128) void qinco_prep(
    const float* __restrict__ cb, const float* __restrict__ Wp,
    const float* __restrict__ bp, const float* __restrict__ W1,
    const float* __restrict__ W2, char* __restrict__ ws) {
    const int blk = blockIdx.x;
    const int t = threadIdx.x;
    __shared__ float row[QD];

    if (blk < 256) {
        float* cpart = (float*)(ws + WS_CPART);
        row[t] = cb[blk * QD + t];
        __syncthreads();
        float acc = bp[t];
        const float* wr = Wp + (size_t)t * (2 * QD) + QD;
        #pragma unroll 8
        for (int e = 0; e < QD; ++e) acc = fmaf(row[e], wr[e], acc);
        cpart[blk * QD + t] = acc;
    } else if (blk < 384) {
        if (t < 64) {
            const int cid = blk - 256;            // b*64 + hc*8 + kc
            const int b = cid >> 6, hc = (cid >> 3) & 7, kc = cid & 7;
            const int m = t & 31, g = t >> 5;
            f16* w1h = (f16*)(ws + WS_W1H);
            f16* w1l = (f16*)(ws + WS_W1H + 131072);
            #pragma unroll
            for (int j = 0; j < 8; ++j) {
                float wv = W1[((size_t)b * QHID + hc * 32 + m) * QD + kc * 16 + g * 8 + j];
                f16 hi = (f16)wv;
                size_t idx = ((size_t)cid * 64 + t) * 8 + j;
                w1h[idx] = hi;
                w1l[idx] = (f16)(wv - (float)hi);
            }
        }
    } else {
        if (t < 64) {
            const int e = blk - 384;              // b*64 + hc*8 + dt*2 + kch
            const int b = e >> 6, hc = (e >> 3) & 7, dt = (e >> 1) & 3, kch = e & 1;
            const int m = t & 31, g = t >> 5;
            f16* w2h = (f16*)(ws + WS_W2H);
            f16* w2l = (f16*)(ws + WS_W2H + 131072);
            #pragma unroll
            for (int j = 0; j < 8; ++j) {
                float wv = W2[((size_t)b * QD + dt * 32 + m) * QHID + hc * 32 + kch * 16 + g * 8 + j];
                f16 hi = (f16)wv;
                size_t idx = ((size_t)e * 64 + t) * 8 + j;
                w2h[idx] = hi;
                w2l[idx] = (f16)(wv - (float)hi);
            }
        }
    }
}

// ---------------------------------------------------------------------------
// Main: grid 8192; block = 4 waves = 128 codes of one n (half = bid&1).
// Cross-iter interleave: GEMM1(i) + GEMM2(i-1); W2 staged one iter behind.
// ---------------------------------------------------------------------------
__global__ __launch_bounds__(256, 2) void qinco_main(
    const float* __restrict__ x, const float* __restrict__ xh,
    const float* __restrict__ Wp,
    const float* __restrict__ b1g, const float* __restrict__ b2g,
    char* __restrict__ ws, float* __restrict__ out) {

    extern __shared__ char smem[];
    const int n = blockIdx.x >> 1;
    const int half = blockIdx.x & 1;
    const int t = threadIdx.x;
    const int w = t >> 6;                 // wave 0..3
    const int l = t & 63;
    const int c32 = l & 31;
    const int g = l >> 5;
    const int baserow = w * 32;

    float* b1_s  = (float*)(smem + L_B1);
    float* b2_s  = (float*)(smem + L_B2);
    float* red_d = (float*)(smem + L_REDD);
    int*   red_i = (int*)(smem + L_REDI);
    float* xp_s  = (float*)(smem + L_XP);
    float* xh_s  = (float*)(smem + L_XH);
    float* r_s   = (float*)(smem + L_RS);

    const float* cpart = (const float*)(ws + WS_CPART);

    // per-wave staging quarter: plane (w>>1: hi/lo), half (w&1)
    const size_t stg = (size_t)(w >> 1) * 131072 + (size_t)(w & 1) * 4096
                     + (size_t)l * 16;
    const size_t dq  = (size_t)(w >> 1) * 8192 + (size_t)(w & 1) * 4096;

    // ---- stage smalls + prologue: stage W1[0] into w1buf[0] ----
    b1_s[t] = b1g[t];
    b1_s[t + 256] = b1g[t + 256];
    if (t < 2 * QD) b2_s[t] = b2g[t];
    if (t < QD) {
        float xv  = x[(size_t)n * QD + t];
        float xhv = xh[(size_t)n * QD + t];
        xh_s[t] = xhv;
        r_s[t]  = xv - xhv;
    }
    {
        const char* s0 = ws + WS_W1H + stg;       // b=0, hc=0
        char* d0 = smem + L_W1B + dq;
        #pragma unroll
        for (int ii = 0; ii < 4; ++ii)
            gload_lds16(s0 + (size_t)ii * 1024, d0 + (size_t)ii * 1024);
    }
    __syncthreads();

    // ---- x_part[d] = sum_e xh[e] * Wp[d,e] ----
    if (t < QD) {
        const float4* wr = (const float4*)(Wp + (size_t)t * (2 * QD));
        const float4* xv = (const float4*)xh_s;
        float acc = 0.f;
        #pragma unroll
        for (int j = 0; j < QD / 4; ++j) {
            float4 a = wr[j], bv = xv[j];
            acc = fmaf(a.x, bv.x, acc);
            acc = fmaf(a.y, bv.y, acc);
            acc = fmaf(a.z, bv.z, acc);
            acc = fmaf(a.w, bv.w, acc);
        }
        xp_s[t] = acc;
    }
    __syncthreads();

    // ---- init C^T acc: 4 tiles of 32x32; codes = half*128 + baserow + c32 ----
    f32x16 Cacc[4];
    {
        const float* cprow = cpart + (size_t)(half * 128 + baserow + c32) * QD;
        #pragma unroll
        for (int dt = 0; dt < 4; ++dt)
            #pragma unroll
            for (int rq = 0; rq < 4; ++rq) {
                const int off = dt * 32 + 8 * rq + 4 * g;
                float4 cp  = *(const float4*)(cprow + off);
                float4 xp4 = *(const float4*)(xp_s + off);
                Cacc[dt][rq * 4 + 0] = cp.x + xp4.x;
                Cacc[dt][rq * 4 + 1] = cp.y + xp4.y;
                Cacc[dt][rq * 4 + 2] = cp.z + xp4.z;
                Cacc[dt][rq * 4 + 3] = cp.w + xp4.w;
            }
    }

    f16x8 cfh[8], cfl[8];
    f16x8 hfh0p, hfl0p, hfh1p, hfl1p;   // hf from previous iter

    // full GEMM2(j) from buffer `wb2p` using hf*p, then + b2(block bb)
    #define GEMM2_DRAIN(wb2p, bb) {                                            \
        __builtin_amdgcn_s_setprio(1);                                         \
        _Pragma("unroll") for (int s = 0; s < 8; ++s) {                        \
            f16x8 w2h = *(const f16x8*)((wb2p) + (size_t)s * 1024);            \
            f16x8 w2l = *(const f16x8*)((wb2p) + 8192 + (size_t)s * 1024);     \
            if ((s & 1) == 0) {                                                \
                Cacc[s >> 1] = MF32(w2h, hfh0p, Cacc[s >> 1]);                 \
                Cacc[s >> 1] = MF32(w2l, hfh0p, Cacc[s >> 1]);                 \
                Cacc[s >> 1] = MF32(w2h, hfl0p, Cacc[s >> 1]);                 \
            } else {                                                           \
                Cacc[s >> 1] = MF32(w2h, hfh1p, Cacc[s >> 1]);                 \
                Cacc[s >> 1] = MF32(w2l, hfh1p, Cacc[s >> 1]);                 \
                Cacc[s >> 1] = MF32(w2h, hfl1p, Cacc[s >> 1]);                 \
            }                                                                  \
        }                                                                      \
        __builtin_amdgcn_s_setprio(0);                                         \
        _Pragma("unroll") for (int dt = 0; dt < 4; ++dt)                       \
        _Pragma("unroll") for (int rq = 0; rq < 4; ++rq) {                     \
            float4 bv = *(const float4*)(b2_s + (bb) * QD + dt * 32            \
                                         + 8 * rq + 4 * g);                    \
            Cacc[dt][rq * 4 + 0] += bv.x;                                      \
            Cacc[dt][rq * 4 + 1] += bv.y;                                      \
            Cacc[dt][rq * 4 + 2] += bv.z;                                      \
            Cacc[dt][rq * 4 + 3] += bv.w;                                      \
        } }

    // ---- main loop ----
    #pragma unroll 1
    for (int iter = 0; iter < 16; ++iter) {
        const int b = iter >> 3;
        const int hc = iter & 7;

        asm volatile("s_waitcnt vmcnt(0)" ::: "memory");
        __builtin_amdgcn_s_barrier();
        asm volatile("" ::: "memory");

        // stage W1[iter+1] and W2[iter]
        if (iter < 15) {
            const int t2 = iter + 1;
            const char* s0 = ws + WS_W1H + (size_t)(t2 >> 3) * 65536
                           + (size_t)(t2 & 7) * 8192 + stg;
            char* d0 = smem + L_W1B + (size_t)(t2 & 1) * 16384 + dq;
            #pragma unroll
            for (int ii = 0; ii < 4; ++ii)
                gload_lds16(s0 + (size_t)ii * 1024, d0 + (size_t)ii * 1024);
        }
        {
            const char* s0 = ws + WS_W2H + (size_t)b * 65536
                           + (size_t)hc * 8192 + stg;
            char* d0 = smem + L_W2B + (size_t)(iter & 1) * 16384 + dq;
            #pragma unroll
            for (int ii = 0; ii < 4; ++ii)
                gload_lds16(s0 + (size_t)ii * 1024, d0 + (size_t)ii * 1024);
        }

        const char* wb2p = (const char*)smem + L_W2B
                         + (size_t)((iter + 1) & 1) * 16384 + (size_t)l * 16;

        if (hc == 0) {
            if (iter == 8)
                GEMM2_DRAIN(wb2p, 0)      // finish GEMM2(7) + b2(block 0)
            // rebuild C fragments for this residual block
            #pragma unroll
            for (int dt = 0; dt < 4; ++dt) {
                split_frags<0>(Cacc[dt], cfh[dt * 2 + 0], cfl[dt * 2 + 0]);
                split_frags<8>(Cacc[dt], cfh[dt * 2 + 1], cfl[dt * 2 + 1]);
            }
        }

        // ---- GEMM1(iter) [+ interleaved GEMM2(iter-1) when hc != 0] ----
        const char* wb1 = (const char*)smem + L_W1B
                        + (size_t)(iter & 1) * 16384 + (size_t)l * 16;
        f32x16 Ha;
        #pragma unroll
        for (int rq = 0; rq < 4; ++rq) {
            float4 bv = *(const float4*)(b1_s + b * QHID + hc * 32 + 8 * rq + 4 * g);
            Ha[rq * 4 + 0] = bv.x;
            Ha[rq * 4 + 1] = bv.y;
            Ha[rq * 4 + 2] = bv.z;
            Ha[rq * 4 + 3] = bv.w;
        }

        __builtin_amdgcn_s_setprio(1);
        if (hc != 0) {
            // s-seq {0,2,4,6,1,3,5,7}: consecutive steps hit different Cacc
            #pragma unroll
            for (int p = 0; p < 8; ++p) {
                const int kc = p;
                const int s = ((p & 3) << 1) | (p >> 2);
                f16x8 wh  = *(const f16x8*)(wb1 + (size_t)kc * 1024);
                f16x8 wl  = *(const f16x8*)(wb1 + 8192 + (size_t)kc * 1024);
                f16x8 w2h = *(const f16x8*)(wb2p + (size_t)s * 1024);
                f16x8 w2l = *(const f16x8*)(wb2p + 8192 + (size_t)s * 1024);
                Ha = MF32(wh, cfh[kc], Ha);
                Ha = MF32(wl, cfh[kc], Ha);
                Ha = MF32(wh, cfl[kc], Ha);
                if (p < 4) {
                    Cacc[p & 3] = MF32(w2h, hfh0p, Cacc[p & 3]);
                    Cacc[p & 3] = MF32(w2l, hfh0p, Cacc[p & 3]);
                    Cacc[p & 3] = MF32(w2h, hfl0p, Cacc[p & 3]);
                } else {
                    Cacc[p & 3] = MF32(w2h, hfh1p, Cacc[p & 3]);
                    Cacc[p & 3] = MF32(w2l, hfh1p, Cacc[p & 3]);
                    Cacc[p & 3] = MF32(w2h, hfl1p, Cacc[p & 3]);
                }
            }
        } else {
            #pragma unroll
            for (int kc = 0; kc < 8; ++kc) {
                f16x8 wh = *(const f16x8*)(wb1 + (size_t)kc * 1024);
                f16x8 wl = *(const f16x8*)(wb1 + 8192 + (size_t)kc * 1024);
                Ha = MF32(wh, cfh[kc], Ha);
                Ha = MF32(wl, cfh[kc], Ha);
                Ha = MF32(wh, cfl[kc], Ha);
            }
        }
        __builtin_amdgcn_s_setprio(0);

        // relu + split -> hf for next iteration's GEMM2
        #pragma unroll
        for (int r = 0; r < 16; ++r) Ha[r] = fmaxf(Ha[r], 0.f);
        split_frags<0>(Ha, hfh0p, hfl0p);
        split_frags<8>(Ha, hfh1p, hfl1p);
    } // iter

    // ---- drain GEMM2(15) + b2(block 1) ----
    asm volatile("s_waitcnt vmcnt(0)" ::: "memory");
    __builtin_amdgcn_s_barrier();
    asm volatile("" ::: "memory");
    {
        const char* wb2p = (const char*)smem + L_W2B + 16384 + (size_t)l * 16;
        GEMM2_DRAIN(wb2p, 1)
    }
    #undef GEMM2_DRAIN

    // ---- distances ----
    float pa = 0.f, pb = 0.f, pc = 0.f, pdm = 0.f;
    #pragma unroll
    for (int dt = 0; dt < 4; ++dt)
        #pragma unroll
        for (int rq = 0; rq < 4; ++rq) {
            float4 rr = *(const float4*)(r_s + dt * 32 + 8 * rq + 4 * g);
            float t0 = rr.x - Cacc[dt][rq * 4 + 0];
            float t1 = rr.y - Cacc[dt][rq * 4 + 1];
            float t2 = rr.z - Cacc[dt][rq * 4 + 2];
            float t3 = rr.w - Cacc[dt][rq * 4 + 3];
            pa = fmaf(t0, t0, pa);
            pb = fmaf(t1, t1, pb);
            pc = fmaf(t2, t2, pc);
            pdm = fmaf(t3, t3, pdm);
        }
    float pd = (pa + pb) + (pc + pdm);
    pd += __shfl_xor(pd, 32);
    if (l < 32) {
        red_d[baserow + l] = pd;
        red_i[baserow + l] = baserow + l;
    }
    __syncthreads();

    // tree argmin over 128 local codes, first-index tie-break
    for (int off = 64; off > 0; off >>= 1) {
        if (t < off) {
            float d2 = red_d[t + off]; int i2 = red_i[t + off];
            float d1 = red_d[t];       int i1 = red_i[t];
            if (d2 < d1 || (d2 == d1 && i2 < i1)) { red_d[t] = d2; red_i[t] = i2; }
        }
        __syncthreads();
    }
    const int lcode = red_i[0];

    // candidate C row -> out scratch region (half0: c_sel slot, half1: x_hat slot)
    float* creg = out + (half == 0 ? (QN + 2 * (size_t)QN * QD) : (size_t)QN)
                + (size_t)n * QD;
    if (w == (lcode >> 5) && c32 == (lcode & 31)) {
        #pragma unroll
        for (int dt = 0; dt < 4; ++dt)
            #pragma unroll
            for (int rq = 0; rq < 4; ++rq)
                *(float4*)(creg + dt * 32 + 8 * rq + 4 * g) =
                    make_float4(Cacc[dt][rq * 4 + 0], Cacc[dt][rq * 4 + 1],
                                Cacc[dt][rq * 4 + 2], Cacc[dt][rq * 4 + 3]);
    }
    if (t == 0) {
        float2* pp = (float2*)(ws + WS_PART);
        pp[n * 2 + half] = make_float2(red_d[0], (float)(half * 128 + lcode));
    }
}

// ---------------------------------------------------------------------------
// Finisher: combine the two halves, write all outputs (R8 verbatim).
// ---------------------------------------------------------------------------
__global__ __launch_bounds__(128) void qinco_fin(
    const float* __restrict__ x, const float* __restrict__ xh,
    const char* __restrict__ ws, float* __restrict__ out) {
    const int n = blockIdx.x;
    const int t = threadIdx.x;
    const float2* pp = (const float2*)(ws + WS_PART);
    float2 p0 = pp[n * 2 + 0];
    float2 p1 = pp[n * 2 + 1];
    const int h = (p1.x < p0.x) ? 1 : 0;   // tie -> half0 (lower indices)
    const float codef = h ? p1.y : p0.y;

    const size_t o_xh = QN + (size_t)n * QD;
    const size_t o_r  = QN + (size_t)QN * QD + (size_t)n * QD;
    const size_t o_cs = QN + 2 * (size_t)QN * QD + (size_t)n * QD;

    float c0 = out[o_cs + t];   // half0 candidate
    float c1 = out[o_xh + t];   // half1 candidate
    float cs = h ? c1 : c0;
    float xhv = xh[(size_t)n * QD + t];
    float xv  = x[(size_t)n * QD + t];

    if (t == 0) out[n] = codef;
    out[o_xh + t] = xhv + cs;
    out[o_r + t]  = xv - xhv;
    out[o_cs + t] = cs;
}

// ---------------------------------------------------------------------------
extern "C" void kernel_launch(void* const* d_in, const int* in_sizes, int n_in,
                              void* d_out, int out_size, void* d_ws, size_t ws_size,
                              hipStream_t stream) {
    const float* x   = (const float*)d_in[0];
    const float* xh  = (const float*)d_in[1];
    const float* cb  = (const float*)d_in[2];
    const float* Wp  = (const float*)d_in[3];
    const float* bp  = (const float*)d_in[4];
    const float* W1  = (const float*)d_in[5];
    const float* b1  = (const float*)d_in[6];
    const float* W2  = (const float*)d_in[7];
    const float* b2  = (const float*)d_in[8];
    float* out = (float*)d_out;

    qinco_prep<<<512, 128, 0, stream>>>(cb, Wp, bp, W1, W2, (char*)d_ws);

    (void)hipFuncSetAttribute((const void*)qinco_main,
                              hipFuncAttributeMaxDynamicSharedMemorySize, L_TOTAL);
    qinco_main<<<2 * QN, 256, L_TOTAL, stream>>>(x, xh, Wp, b1, b2,
                                                 (char*)d_ws, out);
    qinco_fin<<<QN, 128, 0, stream>>>(x, xh, (const char*)d_ws, out);
}